// Round 1
// baseline (233.222 us; speedup 1.0000x reference)
//
#include <hip/hip_runtime.h>

typedef __attribute__((ext_vector_type(8))) short short8;   // 8 x bf16 (4 VGPR)
typedef __attribute__((ext_vector_type(4))) float f32x4;

#define Bsz 4
#define Cin 256
#define Cout 256
#define Hh 64
#define Ww 64
#define HW 4096
#define NG 16
#define EPSV 1e-5f

#define CSTR 40   // col LDS row stride in ushorts: 32 data + 8 pad = 80 B (16B-aligned rows)

static __device__ __forceinline__ unsigned f2bf(float f) {
    unsigned u = __float_as_uint(f);
    return (u + 0x7fffu + ((u >> 16) & 1u)) >> 16;   // RNE bf16
}

static __device__ __forceinline__ float2 ld8(const float* p) {
    float2 v;
    __builtin_memcpy(&v, p, 8);   // 4B-aligned pair load
    return v;
}

// ---------------------------------------------------------------------------
// Kernel 1: weight reorder w[o][c][kk] -> bf16 wtb[ks][o][32],  ks = kk*8 + c/32
// Index inverted vs previous version: thread = OUTPUT element, so the 2B
// stores are fully coalesced (128B/wave); the strided reads hit L2.
// Also zeroes the GN stats accumulators.
// ---------------------------------------------------------------------------
__global__ void wt_kernel(const float* __restrict__ w, ushort* __restrict__ wtb,
                          float* __restrict__ stats) {
    const int i = blockIdx.x * 256 + threadIdx.x;      // over 72*256*32 = 589824
    if (blockIdx.x == 0 && threadIdx.x < 128) stats[threadIdx.x] = 0.f;
    if (i >= 72 * 256 * 32) return;
    const int cl = i & 31;                             // c % 32
    const int o  = (i >> 5) & 255;                     // output channel
    const int ks = i >> 13;                            // K-step 0..71
    const int c  = ((ks & 7) << 5) | cl;
    const int kk = ks >> 3;
    wtb[i] = (ushort)f2bf(w[((size_t)o * Cin + c) * 9 + kk]);
}

// ---------------------------------------------------------------------------
// Kernel 2: fused deformable sampling + bf16 MFMA conv + GN partial stats.
// CHANGE vs prev: block = HALF row (32 px), grid 512 -> 2 blocks/CU so two
// independent barrier groups hide each other's gather latency.
// Block: 512 threads (8 waves): N=32 px, M=256 Co.
// Loop: cc (32-ch chunk) OUTER, kk (tap) INNER -> 9x cache reuse of windows.
// ---------------------------------------------------------------------------
__launch_bounds__(512, 4)
__global__ void dcn_kernel(const float* __restrict__ in,
                           const float* __restrict__ offs,
                           const float* __restrict__ mask,
                           const ushort* __restrict__ wtb,
                           const float* __restrict__ bias,
                           float* __restrict__ out,
                           float* __restrict__ stats) {
    __shared__ int2   s_ta[9 * 32];        // [k][p]: two row base addrs (y*64+xb)
    __shared__ float4 s_tw[9 * 32];        // [k][p]: folded pair weights
    __shared__ ushort s_col[2][32 * CSTR]; // double-buffered col tile (bf16)

    const int t  = threadIdx.x;
    const int bx = blockIdx.x;
    // XCD swizzle: XCD q = bx&7 serves batch q>>1, h-half q&1 (L2 locality).
    // r = bx>>3: r>>1 = h within half, r&1 = which 32-px half of the row.
    const int q  = bx & 7, r = bx >> 3;
    const int b  = q >> 1;
    const int h  = ((q & 1) << 5) | (r >> 1);
    const int wb = (r & 1) << 5;           // pixel base within row: 0 or 32
    const int lane = t & 63;
    const int wv   = t >> 6;               // wave 0..7
    const int px   = lane & 31;            // pixel in half-row
    const int hi   = lane >> 5;            // channel-pair selector
    const int quad = lane >> 4;
    const int l15  = lane & 15;

    // ---- tap precompute: 9 kernel points x 32 pixels ----
    for (int j = t; j < 288; j += 512) {
        const int k = j >> 5, p = j & 31;
        const float* ob = offs + (size_t)b * 18 * HW + h * Ww + wb + p;
        const float dy = ob[(2 * k) * HW];
        const float dx = ob[(2 * k + 1) * HW];
        const float m  = mask[((size_t)b * 9 + k) * HW + h * Ww + wb + p];
        const float y = (float)h + (float)(k / 3 - 1) + dy;
        const float x = (float)(wb + p) + (float)(k % 3 - 1) + dx;
        const float y0f = floorf(y), x0f = floorf(x);
        const float ly = y - y0f, lx = x - x0f;
        const float hy = 1.f - ly, hx = 1.f - lx;
        const int y0 = (int)y0f, x0 = (int)x0f;
        const int yc0 = min(max(y0, 0), 63);
        const int yc1 = min(max(y0 + 1, 0), 63);
        const int xb  = min(max(x0, 0), 62);
        // col-remapped pair coefficients (corner validity folded):
        //   v.x = row[xb], v.y = row[xb+1]
        float ax = 0.f, ay = 0.f;
        if (x0 == xb) {                       // x0 in [0,62]: both corners in-row
            ax = hx;                          // corner x0   -> v.x
            ay = lx;                          // corner x0+1 (<=63) -> v.y
        } else if (x0 < xb) {                 // x0 < 0
            ax = (x0 + 1 == 0) ? lx : 0.f;    // only corner x0+1==0 can be valid
        } else {                              // x0 > 62
            ay = (x0 == 63) ? hx : 0.f;       // x0==63: corner 63 -> v.y;
                                              // x0>=64: both corners OOB -> 0
        }
        const float w0 = (y0 >= 0 && y0 < 64) ? m * hy : 0.f;
        const float w1 = (y0 + 1 >= 0 && y0 + 1 < 64) ? m * ly : 0.f;
        s_ta[j] = make_int2(yc0 * 64 + xb, yc1 * 64 + xb);
        s_tw[j] = make_float4(w0 * ax, w0 * ay, w1 * ax, w1 * ay);
    }
    __syncthreads();

    f32x4 acc[2][2];
#pragma unroll
    for (int i = 0; i < 2; i++)
#pragma unroll
        for (int nt = 0; nt < 2; nt++) acc[i][nt] = (f32x4){0.f, 0.f, 0.f, 0.f};

    const float* inb = in + (size_t)b * Cin * HW;

    // gather 2 samples for step (cc,kk): c = cc*32 + wv*4 + hi*2 + j, pixel px
#define GATHER(cc, kk, pk)                                                 \
    {                                                                      \
        const int2  ad = s_ta[(kk) * 32 + px];                             \
        const float4 tw = s_tw[(kk) * 32 + px];                            \
        const float* cb = inb + (size_t)((cc) * 32 + wv * 4 + hi * 2) * HW;\
        float vv[2];                                                       \
        _Pragma("unroll")                                                  \
        for (int j = 0; j < 2; j++) {                                      \
            const float* pl = cb + j * HW;                                 \
            const float2 g0 = ld8(pl + ad.x);                              \
            const float2 g1 = ld8(pl + ad.y);                              \
            vv[j] = tw.x * g0.x + tw.y * g0.y + tw.z * g1.x + tw.w * g1.y; \
        }                                                                  \
        pk = f2bf(vv[0]) | (f2bf(vv[1]) << 16);                           \
    }

    unsigned pk;
    GATHER(0, 0, pk);                        // prologue: step 0

    int p = 0;
#pragma unroll 1
    for (int s = 0; s < 72; s++) {
        const int cc = s / 9;
        const int kk = s - cc * 9;
        const int ks = kk * 8 + cc;          // K-step index in weight layout
        // publish current samples (1 dword = 2 bf16 channels)
        *(unsigned*)&s_col[p][px * CSTR + wv * 4 + hi * 2] = pk;
        __syncthreads();
        // pipelined gather for next step (overlaps MFMA below)
        if (s < 71) {
            const int s1 = s + 1;
            const int cc1 = s1 / 9;
            GATHER(cc1, s1 - cc1 * 9, pk);
        }
        // A-fragments straight from global (L2-hot, coalesced 1KB/wave)
        const ushort* wp = wtb + ((size_t)(ks * 256 + wv * 32 + l15)) * 32 + quad * 8;
        const short8 a0 = *(const short8*)wp;
        const short8 a1 = *(const short8*)(wp + 16 * 32);
        short8 bfr[2];
#pragma unroll
        for (int nt = 0; nt < 2; nt++)
            bfr[nt] = *(const short8*)&s_col[p][(nt * 16 + l15) * CSTR + quad * 8];
#pragma unroll
        for (int nt = 0; nt < 2; nt++) {
            acc[0][nt] = __builtin_amdgcn_mfma_f32_16x16x32_bf16(a0, bfr[nt], acc[0][nt], 0, 0, 0);
            acc[1][nt] = __builtin_amdgcn_mfma_f32_16x16x32_bf16(a1, bfr[nt], acc[1][nt], 0, 0, 0);
        }
        p ^= 1;
    }
#undef GATHER

    // ---- epilogue: bias, store, GN partial stats ----
    float gs[2], gq[2];
#pragma unroll
    for (int i = 0; i < 2; i++) {
        float s = 0.f, qq = 0.f;
        const int ob = wv * 32 + i * 16 + quad * 4;
#pragma unroll
        for (int reg = 0; reg < 4; reg++) {
            const int o = ob + reg;
            const float bv = bias[o];
            float* op = out + ((size_t)(b * 256 + o)) * HW + h * Ww + wb + l15;
#pragma unroll
            for (int nt = 0; nt < 2; nt++) {
                const float v = acc[i][nt][reg] + bv;
                op[nt * 16] = v;
                s += v;
                qq += v * v;
            }
        }
        gs[i] = s; gq[i] = qq;
    }
#pragma unroll
    for (int off = 32; off; off >>= 1) {
        gs[0] += __shfl_xor(gs[0], off);
        gq[0] += __shfl_xor(gq[0], off);
        gs[1] += __shfl_xor(gs[1], off);
        gq[1] += __shfl_xor(gq[1], off);
    }
    if (lane == 0) {
#pragma unroll
        for (int i = 0; i < 2; i++) {
            const int g = wv * 2 + i;
            atomicAdd(&stats[((size_t)b * NG + g) * 2],     gs[i]);
            atomicAdd(&stats[((size_t)b * NG + g) * 2 + 1], gq[i]);
        }
    }
}

// ---------------------------------------------------------------------------
// Kernel 3: GN apply (mu/rsqrt from accumulated sums, in place)
// ---------------------------------------------------------------------------
__global__ void gn_apply_kernel(float* __restrict__ x, const float* __restrict__ stats,
                                const float* __restrict__ gamma,
                                const float* __restrict__ beta) {
    const int i = blockIdx.x * 256 + threadIdx.x;      // float4 idx, 1048576 total
    const int plane = i >> 10;                         // b*256 + o
    const int o = plane & 255;
    const int bg = plane >> 4;                         // b*16 + g
    const float s = stats[bg * 2], q = stats[bg * 2 + 1];
    const float inv_n = 1.f / 65536.f;
    const float mu = s * inv_n;
    const float var = q * inv_n - mu * mu;
    const float rs = rsqrtf(var + EPSV);
    const float ga = gamma[o] * rs;
    const float be = beta[o] - mu * ga;
    float4 v = ((float4*)x)[i];
    v.x = v.x * ga + be;
    v.y = v.y * ga + be;
    v.z = v.z * ga + be;
    v.w = v.w * ga + be;
    ((float4*)x)[i] = v;
}

// ---------------------------------------------------------------------------
extern "C" void kernel_launch(void* const* d_in, const int* in_sizes, int n_in,
                              void* d_out, int out_size, void* d_ws, size_t ws_size,
                              hipStream_t stream) {
    const float* input  = (const float*)d_in[0];
    const float* offset = (const float*)d_in[1];
    const float* maskp  = (const float*)d_in[2];
    const float* weight = (const float*)d_in[3];
    const float* bias   = (const float*)d_in[4];
    const float* gamma  = (const float*)d_in[5];
    const float* beta   = (const float*)d_in[6];
    float* out = (float*)d_out;

    ushort* wtb  = (ushort*)d_ws;                           // 1.18 MB
    float* stats = (float*)((char*)d_ws + (size_t)Cout * Cin * 9 * sizeof(ushort));

    hipLaunchKernelGGL(wt_kernel, dim3((Cout * Cin * 9 + 255) / 256), dim3(256), 0,
                       stream, weight, wtb, stats);
    hipLaunchKernelGGL(dcn_kernel, dim3(Bsz * Hh * 2), dim3(512), 0, stream,
                       input, offset, maskp, wtb, bias, out, stats);
    hipLaunchKernelGGL(gn_apply_kernel, dim3((Bsz * Cout * HW / 4) / 256), dim3(256), 0,
                       stream, out, stats, gamma, beta);
}

// Round 2
// 190.758 us; speedup vs baseline: 1.2226x; 1.2226x over previous
//
#include <hip/hip_runtime.h>

typedef __attribute__((ext_vector_type(8))) short short8;   // 8 x bf16 (4 VGPR)
typedef __attribute__((ext_vector_type(4))) float f32x4;

#define Bsz 4
#define Cin 256
#define Cout 256
#define Hh 64
#define Ww 64
#define HW 4096
#define NG 16
#define EPSV 1e-5f

#define CSTR 40        // col LDS row stride in ushorts: 32 data + 8 pad = 80 B
#define SPAN 16        // staged input rows per plane (covers |dy| <= ~6.5)
#define PLF (SPAN*64)  // floats per staged plane = 1024

// ---- dynamic LDS layout (bytes) ----
#define OFF_IN   0
#define SZ_IN    (32 * PLF * 4)        // 131072: 32 planes x 16 rows x 64 f32
#define OFF_COL  (OFF_IN + SZ_IN)      // 131072
#define SZ_COL   (2 * 64 * CSTR * 2)   // 10240: double-buffered bf16 col tile
#define OFF_TA   (OFF_COL + SZ_COL)    // 141312
#define SZ_TA    (576 * 8)             // 4608: int2 per tap
#define OFF_TW   (OFF_TA + SZ_TA)      // 145920
#define SZ_TW    (576 * 16)            // 9216: float4 per tap
#define OFF_CTL  (OFF_TW + SZ_TW)      // 155136
#define SMEM_BYTES (OFF_CTL + 16)      // 155152  (< 160 KiB/CU)

static __device__ __forceinline__ unsigned f2bf(float f) {
    unsigned u = __float_as_uint(f);
    return (u + 0x7fffu + ((u >> 16) & 1u)) >> 16;   // RNE bf16
}

static __device__ __forceinline__ float2 ld8(const float* p) {
    float2 v;
    __builtin_memcpy(&v, p, 8);   // 4B-aligned pair load (global or LDS)
    return v;
}

// ---------------------------------------------------------------------------
// Kernel 1: weight reorder w[o][c][kk] -> bf16 wtb[ks][o][32],  ks = kk*8 + c/32
// Thread = OUTPUT element: coalesced 2B stores; strided reads hit L2.
// Also zeroes the GN stats accumulators.
// ---------------------------------------------------------------------------
__global__ void wt_kernel(const float* __restrict__ w, ushort* __restrict__ wtb,
                          float* __restrict__ stats) {
    const int i = blockIdx.x * 256 + threadIdx.x;      // over 72*256*32 = 589824
    if (blockIdx.x == 0 && threadIdx.x < 128) stats[threadIdx.x] = 0.f;
    if (i >= 72 * 256 * 32) return;
    const int cl = i & 31;                             // c % 32
    const int o  = (i >> 5) & 255;                     // output channel
    const int ks = i >> 13;                            // K-step 0..71
    const int c  = ((ks & 7) << 5) | cl;
    const int kk = ks >> 3;
    wtb[i] = (ushort)f2bf(w[((size_t)o * Cin + c) * 9 + kk]);
}

// ---------------------------------------------------------------------------
// Kernel 2: fused deformable sampling + bf16 MFMA conv + GN partial stats.
// CHANGE vs prev: the scattered bilinear gathers now read from an LDS-staged
// row window (rows [ymin, ymin+SPAN) of each 32-ch chunk, staged once per
// chunk via coalesced global_load_lds). This removes the ~4096 scattered
// global address probes per CU-step that were the measured bottleneck
// (~1 probe/cycle/CU). Global fallback path kept for span > SPAN (never on
// N(0,1) offsets).
// Block: 512 threads (8 waves) = one image row (b,h): N=64 px, M=256 Co.
// ---------------------------------------------------------------------------
__launch_bounds__(512, 1)
__global__ void dcn_kernel(const float* __restrict__ in,
                           const float* __restrict__ offs,
                           const float* __restrict__ mask,
                           const ushort* __restrict__ wtb,
                           const float* __restrict__ bias,
                           float* __restrict__ out,
                           float* __restrict__ stats) {
    extern __shared__ char smem[];
    float*  s_in = (float*)(smem + OFF_IN);     // [32][PLF]
    ushort* col  = (ushort*)(smem + OFF_COL);   // [2][64*CSTR]
    int2*   s_ta = (int2*)(smem + OFF_TA);      // [576]
    float4* s_tw = (float4*)(smem + OFF_TW);    // [576]
    int*    s_ctl = (int*)(smem + OFF_CTL);     // [0]=ymin [1]=ymax

    const int t  = threadIdx.x;
    const int bx = blockIdx.x;
    // XCD swizzle: XCD q = bx&7 serves batch q>>1, h-half q&1 (L2 locality)
    const int q  = bx & 7, r = bx >> 3;
    const int b  = q >> 1;
    const int h  = ((q & 1) << 5) | r;
    const int lane = t & 63;
    const int wv   = t >> 6;               // wave 0..7
    const int n    = lane;                 // pixel in row
    const int quad = lane >> 4;
    const int l15  = lane & 15;

    if (t < 2) s_ctl[t] = (t == 0) ? 64 : -1;
    __syncthreads();

    // ---- tap precompute: 9 kernel points x 64 pixels, + block row min/max ----
    int my_min = 64, my_max = -1;
    for (int j = t; j < 576; j += 512) {
        const int k = j >> 6, pp = j & 63;
        const float* ob = offs + (size_t)b * 18 * HW + h * Ww + pp;
        const float dy = ob[(2 * k) * HW];
        const float dx = ob[(2 * k + 1) * HW];
        const float m  = mask[((size_t)b * 9 + k) * HW + h * Ww + pp];
        const float y = (float)h + (float)(k / 3 - 1) + dy;
        const float x = (float)pp + (float)(k % 3 - 1) + dx;
        const float y0f = floorf(y), x0f = floorf(x);
        const float ly = y - y0f, lx = x - x0f;
        const float hy = 1.f - ly, hx = 1.f - lx;
        const int y0 = (int)y0f, x0 = (int)x0f;
        const int yc0 = min(max(y0, 0), 63);
        const int yc1 = min(max(y0 + 1, 0), 63);
        const int xb  = min(max(x0, 0), 62);
        // col-remapped pair coefficients (corner validity folded):
        //   v.x = row[xb], v.y = row[xb+1]
        float ax = 0.f, ay = 0.f;
        if (x0 == xb) {                       // x0 in [0,62]: both corners in-row
            ax = hx;
            ay = lx;
        } else if (x0 < xb) {                 // x0 < 0
            ax = (x0 + 1 == 0) ? lx : 0.f;
        } else {                              // x0 > 62
            ay = (x0 == 63) ? hx : 0.f;
        }
        const float w0 = (y0 >= 0 && y0 < 64) ? m * hy : 0.f;
        const float w1 = (y0 + 1 >= 0 && y0 + 1 < 64) ? m * ly : 0.f;
        s_ta[j] = make_int2(yc0 * 64 + xb, yc1 * 64 + xb);
        s_tw[j] = make_float4(w0 * ax, w0 * ay, w1 * ax, w1 * ay);
        my_min = min(my_min, yc0);
        my_max = max(my_max, yc1);
    }
#pragma unroll
    for (int off = 32; off; off >>= 1) {
        my_min = min(my_min, __shfl_xor(my_min, off));
        my_max = max(my_max, __shfl_xor(my_max, off));
    }
    if (lane == 0) {
        atomicMin(&s_ctl[0], my_min);
        atomicMax(&s_ctl[1], my_max);
    }
    __syncthreads();

    const int ymin = s_ctl[0];
    const bool use_lds = (s_ctl[1] - ymin + 1) <= SPAN;
    const int ymin64 = ymin << 6;

    f32x4 acc[2][4];
#pragma unroll
    for (int i = 0; i < 2; i++)
#pragma unroll
        for (int nt = 0; nt < 4; nt++) acc[i][nt] = (f32x4){0.f, 0.f, 0.f, 0.f};

    const float* inb = in + (size_t)b * Cin * HW;

    // Stage chunk cc's 32 planes x SPAN rows into LDS via async global->LDS.
    // 128 segments of 1KB; wave wv owns segments wv*16..wv*16+15.
    // LDS dest is wave-uniform base + lane*16 (hardware mapping); global src
    // is per-lane with bottom-edge row clamp (staged-but-unread rows only).
#define STAGE(cc)                                                              \
    {                                                                          \
        const float* cbs = inb + (size_t)((cc) * 32) * HW;                     \
        _Pragma("unroll")                                                      \
        for (int i = 0; i < 16; i++) {                                         \
            const int g = (wv << 4) | i;                                       \
            const int plane = g >> 2;                                          \
            const int row = min(ymin + ((g & 3) << 2) + (lane >> 4), 63);      \
            const float* src = cbs + (size_t)plane * HW + row * 64 +           \
                               ((lane & 15) << 2);                             \
            __builtin_amdgcn_global_load_lds(                                  \
                (const __attribute__((address_space(1))) void*)src,            \
                (__attribute__((address_space(3))) void*)(smem + OFF_IN +      \
                                                          g * 1024),          \
                16, 0, 0);                                                     \
        }                                                                      \
    }

    // gather 4 samples for tap kk from the staged LDS window
#define GATHER_L(kk, pk0, pk1)                                             \
    {                                                                      \
        const int2  ad = s_ta[(kk) * 64 + n];                              \
        const float4 tw = s_tw[(kk) * 64 + n];                             \
        const int r0 = ad.x - ymin64, r1 = ad.y - ymin64;                  \
        const float* cb = s_in + (wv << 2) * PLF;                          \
        float vv[4];                                                       \
        _Pragma("unroll")                                                  \
        for (int j = 0; j < 4; j++) {                                      \
            const float* pl = cb + j * PLF;                                \
            const float2 g0 = ld8(pl + r0);                                \
            const float2 g1 = ld8(pl + r1);                                \
            vv[j] = tw.x * g0.x + tw.y * g0.y + tw.z * g1.x + tw.w * g1.y; \
        }                                                                  \
        pk0 = f2bf(vv[0]) | (f2bf(vv[1]) << 16);                           \
        pk1 = f2bf(vv[2]) | (f2bf(vv[3]) << 16);                           \
    }

    // fallback: gather straight from global (old path, span > SPAN only)
#define GATHER_G(cc, kk, pk0, pk1)                                         \
    {                                                                      \
        const int2  ad = s_ta[(kk) * 64 + n];                              \
        const float4 tw = s_tw[(kk) * 64 + n];                             \
        const float* cb = inb + (size_t)((cc) * 32 + wv * 4) * HW;         \
        float vv[4];                                                       \
        _Pragma("unroll")                                                  \
        for (int j = 0; j < 4; j++) {                                      \
            const float* pl = cb + j * HW;                                 \
            const float2 g0 = ld8(pl + ad.x);                              \
            const float2 g1 = ld8(pl + ad.y);                              \
            vv[j] = tw.x * g0.x + tw.y * g0.y + tw.z * g1.x + tw.w * g1.y; \
        }                                                                  \
        pk0 = f2bf(vv[0]) | (f2bf(vv[1]) << 16);                           \
        pk1 = f2bf(vv[2]) | (f2bf(vv[3]) << 16);                           \
    }

#define FRAGS_MFMA(ks, p)                                                      \
    {                                                                          \
        const ushort* wp =                                                     \
            wtb + ((size_t)((ks) * 256 + wv * 32 + l15)) * 32 + quad * 8;      \
        const short8 a0 = *(const short8*)wp;                                  \
        const short8 a1 = *(const short8*)(wp + 16 * 32);                      \
        short8 bfr[4];                                                         \
        _Pragma("unroll")                                                      \
        for (int nt = 0; nt < 4; nt++)                                         \
            bfr[nt] = *(const short8*)&col[(p) * (64 * CSTR) +                 \
                                           (nt * 16 + l15) * CSTR + quad * 8]; \
        _Pragma("unroll")                                                      \
        for (int nt = 0; nt < 4; nt++) {                                       \
            acc[0][nt] = __builtin_amdgcn_mfma_f32_16x16x32_bf16(              \
                a0, bfr[nt], acc[0][nt], 0, 0, 0);                             \
            acc[1][nt] = __builtin_amdgcn_mfma_f32_16x16x32_bf16(              \
                a1, bfr[nt], acc[1][nt], 0, 0, 0);                             \
        }                                                                      \
    }

    unsigned pk0, pk1;
    int p = 0;

    if (use_lds) {
        STAGE(0);
        __syncthreads();                 // drains vmcnt: chunk 0 staged
        GATHER_L(0, pk0, pk1);
#pragma unroll 1
        for (int s = 0; s < 72; s++) {
            const int cc = s / 9;
            const int kk = s - cc * 9;
            const int ks = kk * 8 + cc;
            *(unsigned long long*)&col[p * (64 * CSTR) + n * CSTR + (wv << 2)] =
                (unsigned long long)pk0 | ((unsigned long long)pk1 << 32);
            __syncthreads();
            // all gathers of chunk cc completed before this barrier ->
            // safe to overwrite s_in with chunk cc+1.
            const bool bound = (kk == 8) && (s != 71);
            if (bound) {
                STAGE(cc + 1);           // async loads fly over the MFMAs
            } else if (s != 71) {
                GATHER_L(kk + 1, pk0, pk1);
            }
            FRAGS_MFMA(ks, p);
            if (bound) {
                __syncthreads();         // staging complete (vmcnt drained)
                GATHER_L(0, pk0, pk1);
            }
            p ^= 1;
        }
    } else {
        GATHER_G(0, 0, pk0, pk1);
#pragma unroll 1
        for (int s = 0; s < 72; s++) {
            const int cc = s / 9;
            const int kk = s - cc * 9;
            const int ks = kk * 8 + cc;
            *(unsigned long long*)&col[p * (64 * CSTR) + n * CSTR + (wv << 2)] =
                (unsigned long long)pk0 | ((unsigned long long)pk1 << 32);
            __syncthreads();
            if (s < 71) {
                const int s1 = s + 1;
                const int cc1 = s1 / 9;
                GATHER_G(cc1, s1 - cc1 * 9, pk0, pk1);
            }
            FRAGS_MFMA(ks, p);
            p ^= 1;
        }
    }
#undef STAGE
#undef GATHER_L
#undef GATHER_G
#undef FRAGS_MFMA

    // ---- epilogue: bias, store, GN partial stats ----
    float gs[2], gq[2];
#pragma unroll
    for (int i = 0; i < 2; i++) {
        float s = 0.f, qq = 0.f;
        const int ob = wv * 32 + i * 16 + quad * 4;
#pragma unroll
        for (int reg = 0; reg < 4; reg++) {
            const int o = ob + reg;
            const float bv = bias[o];
            float* op = out + ((size_t)(b * 256 + o)) * HW + h * Ww + l15;
#pragma unroll
            for (int nt = 0; nt < 4; nt++) {
                const float v = acc[i][nt][reg] + bv;
                op[nt * 16] = v;
                s += v;
                qq += v * v;
            }
        }
        gs[i] = s; gq[i] = qq;
    }
#pragma unroll
    for (int off = 32; off; off >>= 1) {
        gs[0] += __shfl_xor(gs[0], off);
        gq[0] += __shfl_xor(gq[0], off);
        gs[1] += __shfl_xor(gs[1], off);
        gq[1] += __shfl_xor(gq[1], off);
    }
    if (lane == 0) {
#pragma unroll
        for (int i = 0; i < 2; i++) {
            const int g = wv * 2 + i;
            atomicAdd(&stats[((size_t)b * NG + g) * 2],     gs[i]);
            atomicAdd(&stats[((size_t)b * NG + g) * 2 + 1], gq[i]);
        }
    }
}

// ---------------------------------------------------------------------------
// Kernel 3: GN apply (mu/rsqrt from accumulated sums, in place)
// ---------------------------------------------------------------------------
__global__ void gn_apply_kernel(float* __restrict__ x, const float* __restrict__ stats,
                                const float* __restrict__ gamma,
                                const float* __restrict__ beta) {
    const int i = blockIdx.x * 256 + threadIdx.x;      // float4 idx, 1048576 total
    const int plane = i >> 10;                         // b*256 + o
    const int o = plane & 255;
    const int bg = plane >> 4;                         // b*16 + g
    const float s = stats[bg * 2], q = stats[bg * 2 + 1];
    const float inv_n = 1.f / 65536.f;
    const float mu = s * inv_n;
    const float var = q * inv_n - mu * mu;
    const float rs = rsqrtf(var + EPSV);
    const float ga = gamma[o] * rs;
    const float be = beta[o] - mu * ga;
    float4 v = ((float4*)x)[i];
    v.x = v.x * ga + be;
    v.y = v.y * ga + be;
    v.z = v.z * ga + be;
    v.w = v.w * ga + be;
    ((float4*)x)[i] = v;
}

// ---------------------------------------------------------------------------
extern "C" void kernel_launch(void* const* d_in, const int* in_sizes, int n_in,
                              void* d_out, int out_size, void* d_ws, size_t ws_size,
                              hipStream_t stream) {
    const float* input  = (const float*)d_in[0];
    const float* offset = (const float*)d_in[1];
    const float* maskp  = (const float*)d_in[2];
    const float* weight = (const float*)d_in[3];
    const float* bias   = (const float*)d_in[4];
    const float* gamma  = (const float*)d_in[5];
    const float* beta   = (const float*)d_in[6];
    float* out = (float*)d_out;

    ushort* wtb  = (ushort*)d_ws;                           // 1.18 MB
    float* stats = (float*)((char*)d_ws + (size_t)Cout * Cin * 9 * sizeof(ushort));

    static int attr_done = 0;
    if (!attr_done) {
        hipFuncSetAttribute((const void*)dcn_kernel,
                            hipFuncAttributeMaxDynamicSharedMemorySize, SMEM_BYTES);
        attr_done = 1;
    }

    hipLaunchKernelGGL(wt_kernel, dim3((Cout * Cin * 9 + 255) / 256), dim3(256), 0,
                       stream, weight, wtb, stats);
    hipLaunchKernelGGL(dcn_kernel, dim3(Bsz * Hh), dim3(512), SMEM_BYTES, stream,
                       input, offset, maskp, wtb, bias, out, stats);
    hipLaunchKernelGGL(gn_apply_kernel, dim3((Bsz * Cout * HW / 4) / 256), dim3(256), 0,
                       stream, out, stats, gamma, beta);
}